// Round 8
// baseline (229.397 us; speedup 1.0000x reference)
//
#include <hip/hip_runtime.h>
#include <stdint.h>

#define D_DIM   512
#define BM      64
#define THREADS 512            // 8 waves; each wave owns 64 N-cols (nt=4)
#define NBLOCKS 2048           // 131072 / 64

typedef __attribute__((ext_vector_type(8))) __bf16 bf16x8;
typedef __attribute__((ext_vector_type(4))) float  f32x4;

__device__ __forceinline__ unsigned short f32_to_bf16_rne(float f) {
    uint32_t u = __builtin_bit_cast(uint32_t, f);
    u += 0x7FFFu + ((u >> 16) & 1u);
    return (unsigned short)(u >> 16);
}

// Repack L (fp32 row-major [K=512][N=512]) into bf16 fragment order:
// flat ushort idx = ((ks*32 + ntg)*64 + lane)*8 + e  holds L[k][n],
//   n = ntg*16 + (lane&15),  k = ks*32 + (lane>>4)*8 + e.
__global__ void prep_lt(const float* __restrict__ L, unsigned short* __restrict__ Ltf) {
    int o = blockIdx.x * 256 + threadIdx.x;
    #pragma unroll
    for (int i = 0; i < 4; ++i) {
        int idx  = o + i * 65536;
        int e    = idx & 7;
        int l    = (idx >> 3) & 63;
        int tile = idx >> 9;
        int ntg  = tile & 31;
        int ks   = tile >> 5;
        int n    = ntg * 16 + (l & 15);
        int k    = ks * 32 + (l >> 4) * 8 + e;
        Ltf[idx] = f32_to_bf16_rne(L[k * 512 + n]);
    }
}

__global__ __launch_bounds__(THREADS, 4)
void psd_main(const float* __restrict__ x, const unsigned short* __restrict__ Ltf,
              const float* __restrict__ b, const float* __restrict__ c,
              float* __restrict__ out) {
    // two fp32 K-quarter slots [64 rows][128 cols], 16B-unit swizzle: stored unit u
    // at row r holds logical unit u ^ (r&15)
    __shared__ __align__(16) float As[2][BM * 128];   // 64 KiB
    __shared__ float wpart[8][BM];
    __shared__ float bpart[BM];

    const int t    = threadIdx.x;
    const int w    = t >> 6;          // wave 0..7
    const int lane = t & 63;
    const int g    = lane >> 4;
    const int ln   = lane & 15;
    const int lo   = lane & 31;       // stage: stored 16B unit
    const int hi   = lane >> 5;       // stage: row parity

    char* AsB = (char*)&As[0][0];
    const char* xB = (const char*)x + (size_t)blockIdx.x * (BM * 2048);
    const float4* b4 = (const float4*)b;

    // fragment-order L base for this wave (ntg = w*4 + nt)
    const unsigned short* LtW = Ltf + (size_t)w * 2048 + (size_t)lane * 8;

    f32x4 acc[4][4];
    #pragma unroll
    for (int m = 0; m < 4; ++m)
        #pragma unroll
        for (int nt = 0; nt < 4; ++nt)
            acc[m][nt] = (f32x4){0.f, 0.f, 0.f, 0.f};
    float bacc = 0.f;

    // Stage quarter Q (fp32 cols [Q*128, Q*128+128)) into slot Q&1.
    // Wave w covers rows [w*8, w*8+8): instr j = rows w*8+2j, w*8+2j+1 (1 KB linear).
    // Lane fetches logical unit (lo ^ (row&15)) so stored unit lo holds it (involution).
#define STAGE(Q)                                                                         \
    {                                                                                    \
        char* ldsw = AsB + ((Q) & 1) * 32768 + w * 4096;                                 \
        _Pragma("unroll")                                                                \
        for (int j = 0; j < 4; ++j) {                                                    \
            const int row = w * 8 + j * 2 + hi;                                          \
            const char* gsrc = xB + (size_t)row * 2048 + (Q) * 512                       \
                             + ((lo ^ (row & 15)) << 4);                                 \
            __builtin_amdgcn_global_load_lds(                                            \
                (const __attribute__((address_space(1))) void*)gsrc,                     \
                (__attribute__((address_space(3))) void*)(ldsw + j * 1024), 16, 0, 0);   \
        }                                                                                \
    }

    // Compute quarter Q from slot Q&1: 4 K-steps of 32.
#define COMPUTE(Q)                                                                       \
    {                                                                                    \
        const char* rb = AsB + ((Q) & 1) * 32768;                                        \
        _Pragma("unroll")                                                                \
        for (int kl = 0; kl < 4; ++kl) {                                                 \
            const int ks = (Q) * 4 + kl;                                                 \
            bf16x8 bfr[4];                                                               \
            _Pragma("unroll")                                                            \
            for (int nt = 0; nt < 4; ++nt)                                               \
                bfr[nt] = *(const bf16x8*)(LtW + (size_t)ks * 16384 + nt * 512);         \
            _Pragma("unroll")                                                            \
            for (int m = 0; m < 4; ++m) {                                                \
                const int row = m * 16 + ln;                                             \
                const int cb  = kl * 8 + g * 2;                                          \
                f32x4 f0 = *(const f32x4*)(rb + row * 512 + (((cb    ) ^ ln) << 4));     \
                f32x4 f1 = *(const f32x4*)(rb + row * 512 + (((cb + 1) ^ ln) << 4));     \
                bf16x8 a;                                                                \
                a[0] = (__bf16)f0[0]; a[1] = (__bf16)f0[1];                              \
                a[2] = (__bf16)f0[2]; a[3] = (__bf16)f0[3];                              \
                a[4] = (__bf16)f1[0]; a[5] = (__bf16)f1[1];                              \
                a[6] = (__bf16)f1[2]; a[7] = (__bf16)f1[3];                              \
                _Pragma("unroll")                                                        \
                for (int nt = 0; nt < 4; ++nt)                                           \
                    acc[m][nt] = __builtin_amdgcn_mfma_f32_16x16x32_bf16(a, bfr[nt], acc[m][nt], 0, 0, 0); \
            }                                                                            \
        }                                                                                \
    }

    // x.b partial from the fp32 slot (reads current slot, pre-barrier safe).
    // Lane covers row w*8+(lane&7), 16B-units cw*4..cw*4+3 (cw = lane>>3).
#define XB_PASS(Q)                                                                       \
    {                                                                                    \
        const char* rb = AsB + ((Q) & 1) * 32768;                                        \
        const int r8  = lane & 7;                                                        \
        const int cw  = lane >> 3;                                                       \
        const int row = w * 8 + r8;                                                      \
        const int rsw = row & 15;                                                        \
        _Pragma("unroll")                                                                \
        for (int i = 0; i < 4; ++i) {                                                    \
            const int unit = cw * 4 + i;                                                 \
            f32x4 xv = *(const f32x4*)(rb + row * 512 + ((unit ^ rsw) << 4));            \
            float4 bv = b4[(Q) * 32 + unit];                                             \
            bacc += xv[0] * bv.x + xv[1] * bv.y + xv[2] * bv.z + xv[3] * bv.w;           \
        }                                                                                \
    }

    STAGE(0)
    __syncthreads();          // drains STAGE(0)
    STAGE(1)                  // flies under COMPUTE(0)
    COMPUTE(0)
    XB_PASS(0)
    __syncthreads();          // drains STAGE(1); all waves done with slot 0
    STAGE(2)
    COMPUTE(1)
    XB_PASS(1)
    __syncthreads();
    STAGE(3)
    COMPUTE(2)
    XB_PASS(2)
    __syncthreads();
    COMPUTE(3)
    XB_PASS(3)

#undef STAGE
#undef COMPUTE
#undef XB_PASS

    // rowsum of squares; C/D layout: col = lane&15, row = 4*(lane>>4) + reg
    #pragma unroll
    for (int m = 0; m < 4; ++m) {
        #pragma unroll
        for (int r = 0; r < 4; ++r) {
            float s = 0.f;
            #pragma unroll
            for (int nt = 0; nt < 4; ++nt) { float vv = acc[m][nt][r]; s += vv * vv; }
            s += __shfl_xor(s, 1);
            s += __shfl_xor(s, 2);
            s += __shfl_xor(s, 4);
            s += __shfl_xor(s, 8);
            if (ln == 0) wpart[w][m * 16 + g * 4 + r] = s;
        }
    }

    // x.b: reduce over the 8 lanes sharing a row (lane bits 3..5 = cw)
    {
        float s = bacc;
        s += __shfl_xor(s, 8);
        s += __shfl_xor(s, 16);
        s += __shfl_xor(s, 32);
        if (lane < 8) bpart[w * 8 + lane] = s;
    }
    __syncthreads();

    if (t < BM) {
        float y = c[0] + bpart[t];
        #pragma unroll
        for (int ww = 0; ww < 8; ++ww) y += wpart[ww][t];
        out[(size_t)blockIdx.x * BM + t] = y;
    }
}

extern "C" void kernel_launch(void* const* d_in, const int* in_sizes, int n_in,
                              void* d_out, int out_size, void* d_ws, size_t ws_size,
                              hipStream_t stream) {
    const float* x = (const float*)d_in[0];
    const float* L = (const float*)d_in[1];
    const float* b = (const float*)d_in[2];
    const float* c = (const float*)d_in[3];
    float* out = (float*)d_out;
    unsigned short* Ltf = (unsigned short*)d_ws;   // 512 KiB

    prep_lt<<<256, 256, 0, stream>>>(L, Ltf);
    psd_main<<<NBLOCKS, THREADS, 0, stream>>>(x, Ltf, b, c, out);
}